// Round 4
// baseline (921.571 us; speedup 1.0000x reference)
//
#include <hip/hip_runtime.h>
#include <hip/hip_fp16.h>
#include <math.h>

// out = gelu( (segment_sum(sem[src,0,:]) / max(cnt,1)) @ W )
// R4: fp16 (e5m10) staging instead of R3's failed bf16 (8x lower quant error,
// same 2B traffic). Gather loop is R2's proven structure with ushort2 loads.

typedef unsigned int   uint32;
typedef unsigned short ushort_t;

__device__ __forceinline__ ushort_t f2h(float f) {
    return __half_as_ushort(__float2half_rn(f));
}
__device__ __forceinline__ float h2f(ushort_t u) {
    return __half2float(__ushort_as_half(u));
}

// ---------------------------------------------------------------------------
// Convert sem[:,0,:] fp32 -> fp16 row-compact (n,128)
__global__ void convert_kernel(const float* __restrict__ sem,
                               ushort_t* __restrict__ semh, int n) {
    int gid = blockIdx.x * blockDim.x + threadIdx.x;  // over n*32 float4s
    if (gid >= n * 32) return;
    int row = gid >> 5, c4 = gid & 31;
    float4 v = ((const float4*)sem)[(size_t)row * 128 + c4];  // row stride 512 f
    ushort4 o;
    o.x = f2h(v.x); o.y = f2h(v.y); o.z = f2h(v.z); o.w = f2h(v.w);
    ((ushort4*)semh)[gid] = o;
}

// ---------------------------------------------------------------------------
// Degree histogram
__global__ void hist_kernel(const int* __restrict__ edges, int* __restrict__ deg,
                            int n_edges) {
    int e = blockIdx.x * blockDim.x + threadIdx.x;
    if (e < n_edges) {
        int2 p = ((const int2*)edges)[e];
        atomicAdd(&deg[p.y], 1);
    }
}

// ---------------------------------------------------------------------------
// Single-workgroup exclusive scan of deg[0..n) -> offs, cursor; offs[n]=total
__global__ __launch_bounds__(1024) void scan_kernel(
    const int* __restrict__ deg, int* __restrict__ offs,
    int* __restrict__ cursor, int n) {
    __shared__ int s[1024];
    const int tid = threadIdx.x;
    const int chunk = (n + 1023) / 1024;
    const int base = tid * chunk;
    const int lim  = min(chunk, n - base);

    int sum = 0;
    for (int i = 0; i < lim; i++) sum += deg[base + i];
    s[tid] = sum;
    __syncthreads();
    for (int off = 1; off < 1024; off <<= 1) {
        int t = (tid >= off) ? s[tid - off] : 0;
        __syncthreads();
        s[tid] += t;
        __syncthreads();
    }
    int run = (tid == 0) ? 0 : s[tid - 1];
    for (int i = 0; i < lim; i++) {
        int idx = base + i;
        offs[idx] = run; cursor[idx] = run;
        run += deg[idx];
    }
    if (tid == 1023) offs[n] = s[1023];
}

// ---------------------------------------------------------------------------
// Scatter edge sources into CSR slots
__global__ void build_csr(const int* __restrict__ edges, int* __restrict__ cursor,
                          int* __restrict__ csr, int n_edges) {
    int e = blockIdx.x * blockDim.x + threadIdx.x;
    if (e < n_edges) {
        int2 p = ((const int2*)edges)[e];
        int pos = atomicAdd(&cursor[p.y], 1);
        csr[pos] = p.x;
    }
}

// ---------------------------------------------------------------------------
// One wave per node (R2-proven structure). Lanes batch-load up to 64 csr
// indices (coalesced), shfl-broadcast each, accumulate fp32. Lane l handles
// columns 2l, 2l+1 (ushort2 = 4B/lane, 256B per source row).
__global__ void gather_mean(const ushort_t* __restrict__ semh,
                            const int* __restrict__ offs,
                            const int* __restrict__ csr,
                            ushort_t* __restrict__ meanh, int n) {
    int gid  = blockIdx.x * blockDim.x + threadIdx.x;
    int node = gid >> 6;
    int lane = gid & 63;
    if (node >= n) return;
    int o0 = offs[node], deg = offs[node + 1] - o0;

    float2 acc = make_float2(0.f, 0.f);
    for (int c = 0; c < deg; c += 64) {
        int m  = min(64, deg - c);
        int sv = (lane < m) ? csr[o0 + c + lane] : 0;
        for (int j = 0; j < m; j++) {
            int s = __shfl(sv, j);
            ushort2 u = ((const ushort2*)(semh + (size_t)s * 128))[lane];
            acc.x += h2f(u.x); acc.y += h2f(u.y);
        }
    }
    float inv = 1.0f / fmaxf((float)deg, 1.0f);
    ushort2 o;
    o.x = f2h(acc.x * inv); o.y = f2h(acc.y * inv);
    ((ushort2*)(meanh + (size_t)node * 128))[lane] = o;
}

// ---------------------------------------------------------------------------
// out = gelu(mean @ W). 32-row tiles, 4 rows x 4 cols per thread, k blocked
// by 4 so both W and m come from LDS as float4 (8 b128 + 64 FMA per k4).
// LDS: 64KB W + 16KB mean -> 80KB -> 2 blocks/CU.
__device__ __forceinline__ float gelu_exact(float x) {
    return 0.5f * x * (1.0f + erff(x * 0.70710678118654752f));
}

__global__ __launch_bounds__(256, 2) void finalize_kernel(
    const ushort_t* __restrict__ meanh, const float* __restrict__ W,
    float* __restrict__ out, int n) {
    __shared__ float Wl[128 * 128];
    __shared__ float ml[32 * 128];

    for (int i = threadIdx.x; i < 128 * 32; i += 256)
        ((float4*)Wl)[i] = ((const float4*)W)[i];

    const int rg = threadIdx.x >> 5;   // 0..7 -> rows rg, rg+8, rg+16, rg+24
    const int cg = threadIdx.x & 31;   // col group of 4
    const int rowsPerIter = 32 * gridDim.x;

    for (int row0 = blockIdx.x * 32; row0 < n; row0 += rowsPerIter) {
        __syncthreads();  // W ready (iter0) / prev ml reads done
        // stage 32 mean rows fp16->fp32 (1024 ushort4 slots / 256 thr = 4 ea)
        #pragma unroll
        for (int p = 0; p < 4; p++) {
            int i  = threadIdx.x + 256 * p;
            int rr = i >> 5, k4 = i & 31;
            int row = row0 + rr;
            float4 v = make_float4(0.f, 0.f, 0.f, 0.f);
            if (row < n) {
                ushort4 u = ((const ushort4*)(meanh + (size_t)row * 128))[k4];
                v = make_float4(h2f(u.x), h2f(u.y), h2f(u.z), h2f(u.w));
            }
            ((float4*)ml)[i] = v;
        }
        __syncthreads();

        float4 a0 = make_float4(0.f,0.f,0.f,0.f), a1 = a0, a2 = a0, a3 = a0;
        #pragma unroll 8
        for (int k4 = 0; k4 < 32; k4++) {
            float4 m0 = ((const float4*)(ml + (rg     ) * 128))[k4];
            float4 m1 = ((const float4*)(ml + (rg +  8) * 128))[k4];
            float4 m2 = ((const float4*)(ml + (rg + 16) * 128))[k4];
            float4 m3 = ((const float4*)(ml + (rg + 24) * 128))[k4];
            #pragma unroll
            for (int kk = 0; kk < 4; kk++) {
                float4 wv = ((const float4*)(Wl + (k4 * 4 + kk) * 128))[cg];
                float v0 = (kk==0)?m0.x:(kk==1)?m0.y:(kk==2)?m0.z:m0.w;
                float v1 = (kk==0)?m1.x:(kk==1)?m1.y:(kk==2)?m1.z:m1.w;
                float v2 = (kk==0)?m2.x:(kk==1)?m2.y:(kk==2)?m2.z:m2.w;
                float v3 = (kk==0)?m3.x:(kk==1)?m3.y:(kk==2)?m3.z:m3.w;
                a0.x = fmaf(v0, wv.x, a0.x); a0.y = fmaf(v0, wv.y, a0.y);
                a0.z = fmaf(v0, wv.z, a0.z); a0.w = fmaf(v0, wv.w, a0.w);
                a1.x = fmaf(v1, wv.x, a1.x); a1.y = fmaf(v1, wv.y, a1.y);
                a1.z = fmaf(v1, wv.z, a1.z); a1.w = fmaf(v1, wv.w, a1.w);
                a2.x = fmaf(v2, wv.x, a2.x); a2.y = fmaf(v2, wv.y, a2.y);
                a2.z = fmaf(v2, wv.z, a2.z); a2.w = fmaf(v2, wv.w, a2.w);
                a3.x = fmaf(v3, wv.x, a3.x); a3.y = fmaf(v3, wv.y, a3.y);
                a3.z = fmaf(v3, wv.z, a3.z); a3.w = fmaf(v3, wv.w, a3.w);
            }
        }
        #pragma unroll
        for (int q = 0; q < 4; q++) {
            float4 a = (q == 0) ? a0 : (q == 1) ? a1 : (q == 2) ? a2 : a3;
            int row = row0 + rg + 8 * q;
            if (row < n) {
                float4 g = make_float4(gelu_exact(a.x), gelu_exact(a.y),
                                       gelu_exact(a.z), gelu_exact(a.w));
                ((float4*)(out + (size_t)row * 128))[cg] = g;
            }
        }
    }
}

// ---------------------------------------------------------------------------
extern "C" void kernel_launch(void* const* d_in, const int* in_sizes, int n_in,
                              void* d_out, int out_size, void* d_ws, size_t ws_size,
                              hipStream_t stream) {
    const float* sem   = (const float*)d_in[0];
    const float* W     = (const float*)d_in[2];
    const int*   edges = (const int*)d_in[3];

    const int n       = in_sizes[0] / (4 * 128);  // 100000
    const int n_edges = in_sizes[3] / 2;          // 1600000

    auto align16 = [](size_t x) { return (x + 15) & ~(size_t)15; };
    char* p = (char*)d_ws;
    int*      deg    = (int*)p;       p += align16((size_t)n * 4);
    int*      offs   = (int*)p;       p += align16((size_t)(n + 1) * 4);
    int*      cursor = (int*)p;       p += align16((size_t)n * 4);
    int*      csr    = (int*)p;       p += align16((size_t)n_edges * 4);
    ushort_t* semh   = (ushort_t*)p;  p += align16((size_t)n * 128 * 2);
    ushort_t* meanh  = (ushort_t*)p;  // n*128 fp16

    hipMemsetAsync(deg, 0, (size_t)n * 4, stream);

    const int T = 256;
    const int eblocks = (n_edges + T - 1) / T;
    const int cblocks = (n * 32 + T - 1) / T;

    convert_kernel<<<cblocks, T, 0, stream>>>(sem, semh, n);
    hist_kernel   <<<eblocks, T, 0, stream>>>(edges, deg, n_edges);
    scan_kernel   <<<1,    1024, 0, stream>>>(deg, offs, cursor, n);
    build_csr     <<<eblocks, T, 0, stream>>>(edges, cursor, csr, n_edges);

    const int gblocks = (int)(((long long)n * 64 + T - 1) / T);
    gather_mean   <<<gblocks, T, 0, stream>>>(semh, offs, csr, meanh, n);

    finalize_kernel<<<512,    T, 0, stream>>>(meanh, W, (float*)d_out, n);
}